// Round 2
// baseline (899.584 us; speedup 1.0000x reference)
//
#include <hip/hip_runtime.h>
#include <math.h>

// Problem constants (match reference)
#define NCLS 330          // C_CLASSES
#define NCOL2 165         // 330/2 float2 per row
static constexpr float EPSV = 0.1f;
static constexpr float LAMV = 0.25f;

// Real principal-branch Lambert W, matching reference algorithm in f32.
// Computed once per row (one lane per row) -> cost negligible.
__device__ __forceinline__ float lambertw_f(float y) {
    float p  = sqrtf(fmaxf(2.0f * (2.7182817f * y + 1.0f), 0.0f));
    float wb = -1.0f + p - p * p * (1.0f / 3.0f) + (11.0f / 72.0f) * p * p * p;
    float w  = (y < 0.3f) ? wb : log1pf(y);
#pragma unroll
    for (int i = 0; i < 6; ++i) {
        float ew   = __expf(w);
        float f    = w * ew - y;
        float wp1  = w + 1.0f;
        float swp1 = (fabsf(wp1) < 1e-12f) ? 1e-12f : wp1;
        float den  = ew * wp1 - (w + 2.0f) * f / (2.0f * swp1);
        float sden = (fabsf(den) < 1e-30f) ? 1e-30f : den;
        float step = (fabsf(f) < 1e-30f) ? 0.0f : f / sden;
        w -= step;
    }
    return w;
}

// DPP add: v + dpp_perm(v). Pure VALU (2 instrs), no LDS pipe, no waitcnt.
// CTRL must be an IMMEDIATE for __builtin_amdgcn_update_dpp -> template param.
// 0xB1 = quad_perm(1,0,3,2) [xor1], 0x4E = quad_perm(2,3,0,1) [xor2],
// 0x124 = row_ror:4, 0x128 = row_ror:8 (rotations within 16-lane row;
// ror4+ror8 after the two quad_perms sums all four quad-partials on every
// lane of the 16-lane group).
template <int CTRL>
__device__ __forceinline__ float dpp_add(float v) {
    int t = __builtin_amdgcn_update_dpp(0, __float_as_int(v), CTRL, 0xF, 0xF, true);
    return v + __int_as_float(t);
}

// One wave owns 64 consecutive rows (streams 84.5 KB contiguous).
// Per row: 3 coalesced float2 loads, 6 expf, 4 DPP adds (16-lane group sum),
// ONE predicated ds_write of the 4 group partials into a [64][4] transpose
// buffer. NO per-row cross-lane LDS ops (the old kernel's 8 dependent
// ds_bpermute per row were the serialization). After the loop, lane L reads
// its own row's 4 partials (1x ds_read_b128), finishes log/LambertW per-lane,
// and the wave-wide butterflies run once per wave instead of once per row.
// x[target] is loaded directly per lane (address known up-front), removing
// the per-row target-broadcast shuffles entirely.
#define ROW_BODY(R)                                                           \
    {                                                                         \
        const float2* xr2 = (const float2*)(x + (size_t)(base + (R)) * NCLS); \
        float2 a0 = xr2[lane];                                                \
        float2 a1 = xr2[lane + 64];                                           \
        float2 a2 = has2 ? xr2[lane + 128] : make_float2(0.0f, 0.0f);         \
        float se = __expf(a0.x) + __expf(a0.y) + __expf(a1.x) + __expf(a1.y); \
        float sx = a0.x + a0.y + a1.x + a1.y;                                 \
        if (has2) {                                                           \
            se += __expf(a2.x) + __expf(a2.y);                                \
            sx += a2.x + a2.y;                                                \
        }                                                                     \
        acc_sx += sx;                                                         \
        se = dpp_add<0xB1>(se);                                               \
        se = dpp_add<0x4E>(se);                                               \
        se = dpp_add<0x124>(se);                                              \
        se = dpp_add<0x128>(se);                                              \
        if (gleader) s_row[(R) * 4 + grp] = se;                               \
    }

__global__ __launch_bounds__(256) void superloss_main(
    const float* __restrict__ x, const int* __restrict__ tgt,
    double* __restrict__ ws, int B)
{
    const int lane = threadIdx.x & 63;
    const int wid  = threadIdx.x >> 6;
    const int gw   = blockIdx.x * 4 + wid;
    const int base = gw * 64;

    __shared__ __align__(16) float s_se[4][64][4];   // [wave][row][16-grp], 4 KB
    __shared__ double s_sm[4], s_sp[4];

    int nrows = B - base;
    nrows = (nrows > 64) ? 64 : (nrows < 0 ? 0 : nrows);

    const bool has2    = lane < (NCOL2 - 128);   // 37 lanes carry a 3rd float2
    const int  grp     = lane >> 4;              // 16-lane group 0..3
    const bool gleader = (lane & 15) == 0;
    float*     s_row   = &s_se[wid][0][0];

    // own-row target value: address known up-front, issue before the loop so
    // the (single) miss overlaps the whole streaming phase.
    int   t_own = 0;
    float xt    = 0.0f;
    if (lane < nrows) {
        t_own = tgt[base + lane];
        xt    = x[(size_t)(base + lane) * NCLS + t_own];
    }

    float acc_sx = 0.0f;   // per-lane partial of sum_x over all rows

    if (nrows == 64) {
#pragma unroll 4
        for (int r = 0; r < 64; ++r) ROW_BODY(r)
    } else {
        for (int r = 0; r < nrows; ++r) ROW_BODY(r)
    }
    __syncthreads();

    // per-lane epilogue: lane L finishes row base+L
    float sm_l = -acc_sx;
    float sp_l = 0.0f;
    if (lane < nrows) {
        const float4 p = *(const float4*)&s_se[wid][lane][0];
        float se_t = (p.x + p.y) + (p.z + p.w);
        float lse  = __logf(se_t);     // |x|<7 -> unshifted lse f32-exact
        float li   = lse - xt;
        sm_l += (float)NCLS * lse;

        const float tau = logf((float)NCLS);
        float y     = 0.5f * fmaxf(-0.73575888f, (li - tau) * (1.0f / LAMV));
        float w     = lambertw_f(y);
        float sigma = __expf(-w);
        sp_l = (li - tau) * sigma + LAMV * w * w;
    }

    // one butterfly per wave (was: one per row)
#pragma unroll
    for (int m = 32; m > 0; m >>= 1) {
        sm_l += __shfl_xor(sm_l, m, 64);
        sp_l += __shfl_xor(sp_l, m, 64);
    }

    if (lane == 0) { s_sm[wid] = (double)sm_l; s_sp[wid] = (double)sp_l; }
    __syncthreads();
    if (threadIdx.x == 0) {
        double sm = s_sm[0] + s_sm[1] + s_sm[2] + s_sm[3];
        double sp = s_sp[0] + s_sp[1] + s_sp[2] + s_sp[3];
        atomicAdd(&ws[0], sm);   // 2048 atomics/addr total: negligible
        atomicAdd(&ws[1], sp);
    }
}

__global__ void superloss_final(const double* __restrict__ ws,
                                float* __restrict__ out, int B)
{
    double mean_smooth = ws[0] / (double)B;
    double mean_super  = ws[1] / (double)B;
    out[0] = (float)(mean_smooth * ((double)EPSV / (double)NCLS)
                     + (1.0 - (double)EPSV) * mean_super);
}

extern "C" void kernel_launch(void* const* d_in, const int* in_sizes, int n_in,
                              void* d_out, int out_size, void* d_ws, size_t ws_size,
                              hipStream_t stream) {
    const float* x   = (const float*)d_in[0];
    const int*   tgt = (const int*)d_in[1];
    const int    B   = in_sizes[1];          // target count = batch
    double*      ws  = (double*)d_ws;

    (void)hipMemsetAsync(ws, 0, 2 * sizeof(double), stream);  // ws re-poisoned each call

    const int grid = (B + 255) / 256;        // 4 waves/block, 64 rows/wave
    superloss_main<<<grid, 256, 0, stream>>>(x, tgt, ws, B);
    superloss_final<<<1, 1, 0, stream>>>(ws, (float*)d_out, B);
}